// Round 11
// baseline (1165.625 us; speedup 1.0000x reference)
//
#include <hip/hip_runtime.h>
#include <hip/hip_cooperative_groups.h>
#include <math.h>

namespace cg = cooperative_groups;

#define N_NODES 50000
#define N_EDGES 600000
#define F 128
#define NT 4
#define ZC 640                 // Z columns = 5 planes x 128
#define N_SEG (NT * N_NODES)   // 200000
#define SCAN_BLK 196           // ceil(N_SEG / 1024)
#define NKT 4                  // K chunks of 32 (K=128)
#define NCT 40                 // global 16-col tiles (640/16)
#define PERLAYER (NKT * NCT * 64)   // 10240 fragments
#define WELEM (PERLAYER * 8)        // 81920 bf16 elements per layer
#define GEMM_TILES ((N_NODES + 63) / 64)   // 782

typedef __attribute__((ext_vector_type(8))) short bf16x8;
typedef __attribute__((ext_vector_type(4))) float f32x4;

__device__ __forceinline__ unsigned short f2b(float f) {
    unsigned u = __float_as_uint(f);
    return (unsigned short)((u + 0x7FFFu + ((u >> 16) & 1u)) >> 16);
}
__device__ __forceinline__ float b2f(unsigned short h) {
    return __uint_as_float(((unsigned)h) << 16);
}

// ---------------- gemm tile body (proven R10 code, parameterized) ----------------
__device__ __forceinline__ void gemm_tile(
    int nodeBase, int fp32in,
    const float* __restrict__ Xf,
    const unsigned short* __restrict__ Xh, const unsigned short* __restrict__ Xl,
    const unsigned short* __restrict__ Wh, const unsigned short* __restrict__ Wl,
    unsigned short* __restrict__ Z,
    unsigned short (*AhS)[136], unsigned short (*AlS)[136],
    int tid, int lane, int w, int quad, int l15)
{
    __syncthreads();   // protect LDS reuse across tile iterations
    // stage full 64x128 A tile (hi/lo) once
    {
        int r = tid >> 2;
        int cb = (tid & 3) * 32;
        int n = nodeBase + r;
        int nc = n < N_NODES ? n : N_NODES - 1;
        if (fp32in) {
            const float* src = Xf + (size_t)nc * F;
#pragma unroll
            for (int i = 0; i < 8; ++i) {
                int cc = cb + i * 4;
                float4 v = *(const float4*)(src + cc);
                ushort4 hi, lo;
                hi.x = f2b(v.x); lo.x = f2b(v.x - b2f(hi.x));
                hi.y = f2b(v.y); lo.y = f2b(v.y - b2f(hi.y));
                hi.z = f2b(v.z); lo.z = f2b(v.z - b2f(hi.z));
                hi.w = f2b(v.w); lo.w = f2b(v.w - b2f(hi.w));
                *(ushort4*)&AhS[r][cc] = hi;
                *(ushort4*)&AlS[r][cc] = lo;
            }
        } else {
            const unsigned short* sh = Xh + (size_t)nc * F;
            const unsigned short* sl = Xl + (size_t)nc * F;
#pragma unroll
            for (int i = 0; i < 4; ++i) {
                int cc = cb + i * 8;
                *(uint4*)&AhS[r][cc] = *(const uint4*)(sh + cc);
                *(uint4*)&AlS[r][cc] = *(const uint4*)(sl + cc);
            }
        }
    }
    __syncthreads();

    const bf16x8* Bh = (const bf16x8*)Wh;
    const bf16x8* Bl = (const bf16x8*)Wl;

    for (int cp = 0; cp < 5; ++cp) {
        f32x4 acc[4][2];
#pragma unroll
        for (int rt = 0; rt < 4; ++rt)
#pragma unroll
            for (int ci = 0; ci < 2; ++ci)
                acc[rt][ci] = (f32x4){0.f, 0.f, 0.f, 0.f};

#pragma unroll
        for (int kt = 0; kt < NKT; ++kt) {
            bf16x8 bh[2], bl[2];
#pragma unroll
            for (int ci = 0; ci < 2; ++ci) {
                int gct = cp * 8 + w * 2 + ci;
                int fi = (kt * NCT + gct) * 64 + lane;
                bh[ci] = Bh[fi];
                bl[ci] = Bl[fi];
            }
            bf16x8 ah[4], al[4];
#pragma unroll
            for (int rt = 0; rt < 4; ++rt) {
                int row = rt * 16 + l15;
                ah[rt] = *(const bf16x8*)&AhS[row][kt * 32 + quad * 8];
                al[rt] = *(const bf16x8*)&AlS[row][kt * 32 + quad * 8];
            }
#pragma unroll
            for (int rt = 0; rt < 4; ++rt)
#pragma unroll
                for (int ci = 0; ci < 2; ++ci) {
                    acc[rt][ci] = __builtin_amdgcn_mfma_f32_16x16x32_bf16(ah[rt], bh[ci], acc[rt][ci], 0, 0, 0);
                    acc[rt][ci] = __builtin_amdgcn_mfma_f32_16x16x32_bf16(ah[rt], bl[ci], acc[rt][ci], 0, 0, 0);
                    acc[rt][ci] = __builtin_amdgcn_mfma_f32_16x16x32_bf16(al[rt], bh[ci], acc[rt][ci], 0, 0, 0);
                }
        }

        // store plane cp; C/D layout col=lane&15, row=quad*4+reg
#pragma unroll
        for (int rt = 0; rt < 4; ++rt)
#pragma unroll
            for (int r = 0; r < 4; ++r) {
                int row = rt * 16 + quad * 4 + r;
                int n = nodeBase + row;
                if (n < N_NODES) {
                    size_t base = (size_t)n * ZC + cp * F + w * 32;
                    Z[base + l15]      = f2b(acc[rt][0][r]);
                    Z[base + 16 + l15] = f2b(acc[rt][1][r]);
                }
            }
    }
}

// ---------------- gather body (proven R10 code, parameterized) ----------------
__device__ __forceinline__ void gather_node(
    int node, int lane,
    const unsigned short* __restrict__ Z,
    const unsigned long long* __restrict__ perm64,
    const int* __restrict__ off, const int* __restrict__ segend,
    const float* __restrict__ bias,
    float* __restrict__ outF, unsigned short* __restrict__ outH,
    unsigned short* __restrict__ outL, int doNormRelu)
{
    int start = off[node * NT];
    int end   = segend[node * NT + NT - 1];

    unsigned su = ((const unsigned*)(Z + (size_t)node * ZC))[lane];

    float sx = 0.f, sy = 0.f;
    const uint2* P = (const uint2*)perm64;

    for (int b = start; b < end; b += 16) {
        int pidx = b + (lane & 15);
        uint2 pk = P[pidx < end ? pidx : end - 1];
        int nb = end - b;                     // wave-uniform
        unsigned uv[16];
        float scl[16];
#pragma unroll
        for (int i = 0; i < 16; ++i) {
            if (i < nb) {
                unsigned offw = __shfl(pk.x, i);
                scl[i] = __uint_as_float(__shfl(pk.y, i));
                uv[i] = ((const unsigned*)(Z + offw))[lane];
            }
        }
#pragma unroll
        for (int i = 0; i < 16; ++i) {
            if (i < nb) {
                sx = fmaf(__uint_as_float(uv[i] << 16), scl[i], sx);
                sy = fmaf(__uint_as_float(uv[i] & 0xffff0000u), scl[i], sy);
            }
        }
    }

    float2 bv = ((const float2*)bias)[lane];
    float vx = __uint_as_float(su << 16) + sx + bv.x;
    float vy = __uint_as_float(su & 0xffff0000u) + sy + bv.y;

    if (doNormRelu) {
        float loc = vx * vx + vy * vy;
#pragma unroll
        for (int ofs = 1; ofs < 64; ofs <<= 1) loc += __shfl_xor(loc, ofs);
        float sc = 1.0f / fmaxf(sqrtf(loc), 1e-12f);
        vx = fmaxf(vx * sc, 0.0f);
        vy = fmaxf(vy * sc, 0.0f);
        unsigned short hx = f2b(vx), hy = f2b(vy);
        unsigned short lx = f2b(vx - b2f(hx)), ly = f2b(vy - b2f(hy));
        ((unsigned*)(outH + (size_t)node * F))[lane] = (unsigned)hx | ((unsigned)hy << 16);
        ((unsigned*)(outL + (size_t)node * F))[lane] = (unsigned)lx | ((unsigned)ly << 16);
    } else {
        ((float2*)(outF + (size_t)node * F))[lane] = make_float2(vx, vy);
    }
}

// ================ single cooperative kernel: whole pipeline ================
__global__ __launch_bounds__(256, 3) void fused_all(
    const float* __restrict__ x,
    const float* __restrict__ Ws1, const float* __restrict__ Wn1, const float* __restrict__ b1,
    const float* __restrict__ Ws2, const float* __restrict__ Wn2, const float* __restrict__ b2,
    const int* __restrict__ srcA, const int* __restrict__ dstA, const int* __restrict__ typA,
    unsigned short* __restrict__ Z,
    unsigned short* __restrict__ h1h, unsigned short* __restrict__ h1l,
    float* __restrict__ bavg,
    unsigned short* __restrict__ Whsw, unsigned short* __restrict__ Wlsw,
    int* __restrict__ counts, int* __restrict__ cursor, int* __restrict__ bsum,
    unsigned long long* __restrict__ perm64,
    float* __restrict__ outF)
{
    cg::grid_group grid = cg::this_grid();
    __shared__ unsigned short AhS[64][136];
    __shared__ unsigned short AlS[64][136];
    __shared__ int sh[256];

    const int G = gridDim.x;
    const int tid = threadIdx.x;
    const int gsz = G * 256;
    const int gtid = blockIdx.x * 256 + tid;
    const int lane = tid & 63;
    const int w = tid >> 6;
    const int quad = lane >> 4;
    const int l15 = lane & 15;

    // ---- phase 0: zero counts + build combined/split/swizzled weights + bias ----
    for (int i = gtid; i < N_SEG + 2; i += gsz) counts[i] = 0;
    for (int idx = gtid; idx < 2 * PERLAYER + 2 * F; idx += gsz) {
        if (idx < 2 * PERLAYER) {
            int l = idx >= PERLAYER;
            int rem = idx - l * PERLAYER;
            int ln = rem & 63;
            int gct = (rem >> 6) % NCT;
            int kt = (rem >> 6) / NCT;
            const float* Wsl = l ? Ws2 : Ws1;
            const float* Wnl = l ? Wn2 : Wn1;
            unsigned short* oh = Whsw + (size_t)l * WELEM + (size_t)rem * 8;
            unsigned short* ol = Wlsw + (size_t)l * WELEM + (size_t)rem * 8;
            int c = gct * 16 + (ln & 15);
            int p = c >> 7;
            int cc = c & (F - 1);
            int kbase = kt * 32 + (ln >> 4) * 8;
#pragma unroll
            for (int j = 0; j < 8; ++j) {
                int k = kbase + j;
                float v;
                if (p == 0) {
                    v = 0.25f * (Wsl[(0 * F + k) * F + cc] + Wsl[(1 * F + k) * F + cc] +
                                 Wsl[(2 * F + k) * F + cc] + Wsl[(3 * F + k) * F + cc]);
                } else {
                    v = 0.25f * Wnl[((p - 1) * F + k) * F + cc];
                }
                unsigned short h = f2b(v);
                oh[j] = h;
                ol[j] = f2b(v - b2f(h));
            }
        } else {
            int k = idx - 2 * PERLAYER;
            int l = k >> 7;
            int j = k & (F - 1);
            const float* bl = l ? b2 : b1;
            bavg[k] = 0.25f * (bl[j] + bl[F + j] + bl[2 * F + j] + bl[3 * F + j]);
        }
    }
    grid.sync();

    // ---- phase 1: histogram ----
    for (int e = gtid; e < N_EDGES; e += gsz)
        atomicAdd(&counts[dstA[e] * NT + typA[e]], 1);
    grid.sync();

    // ---- phase 2a: per-group (1024-elem) exclusive scan; totals -> bsum ----
    for (int g = blockIdx.x; g < SCAN_BLK; g += G) {
        __syncthreads();
        int base = g * 1024 + tid * 4;
        int v[4];
        int tot = 0;
#pragma unroll
        for (int j = 0; j < 4; ++j) {
            int i = base + j;
            v[j] = (i < N_SEG) ? counts[i] : 0;
            tot += v[j];
        }
        sh[tid] = tot;
        __syncthreads();
        for (int ofs = 1; ofs < 256; ofs <<= 1) {
            int add = (tid >= ofs) ? sh[tid - ofs] : 0;
            __syncthreads();
            sh[tid] += add;
            __syncthreads();
        }
        int excl = (tid > 0) ? sh[tid - 1] : 0;
        if (tid == 255) bsum[g] = sh[255];
#pragma unroll
        for (int j = 0; j < 4; ++j) {
            int i = base + j;
            if (i < N_SEG) counts[i] = excl;
            excl += v[j];
        }
    }
    grid.sync();

    // ---- phase 2b: block 0 scans the 196 group totals ----
    if (blockIdx.x == 0) {
        sh[tid] = (tid < SCAN_BLK) ? bsum[tid] : 0;
        __syncthreads();
        for (int ofs = 1; ofs < 256; ofs <<= 1) {
            int add = (tid >= ofs) ? sh[tid - ofs] : 0;
            __syncthreads();
            sh[tid] += add;
            __syncthreads();
        }
        int excl = (tid > 0) ? sh[tid - 1] : 0;
        if (tid < SCAN_BLK) bsum[tid] = excl;
    }
    grid.sync();

    // ---- phase 2c: finalize offsets in place; copy to cursor; sentinel ----
    for (int i = gtid; i < N_SEG; i += gsz) {
        int v = counts[i] + bsum[i >> 10];
        counts[i] = v;
        cursor[i] = v;
    }
    if (gtid == 0) counts[N_SEG] = N_EDGES;
    grid.sync();

    // ---- phase 3: permute edges into buckets with packed (scale, elem-offset) ----
    for (int e = gtid; e < N_EDGES; e += gsz) {
        int t = typA[e];
        int seg = dstA[e] * NT + t;
        int pos = atomicAdd(&cursor[seg], 1);
        float invv = 1.0f / fmaxf((float)(counts[seg + 1] - counts[seg]), 1.0f);
        unsigned offw = (unsigned)(srcA[e] * ZC + (t + 1) * F);
        perm64[pos] = ((unsigned long long)__float_as_uint(invv) << 32) | offw;
    }
    grid.sync();

    // ---- phase 4: gemm layer 1 (fp32 input x) ----
    for (int tile = blockIdx.x; tile < GEMM_TILES; tile += G)
        gemm_tile(tile * 64, 1, x, (const unsigned short*)nullptr, (const unsigned short*)nullptr,
                  Whsw, Wlsw, Z, AhS, AlS, tid, lane, w, quad, l15);
    grid.sync();

    // ---- phase 5: gather layer 1 (norm+relu, pre-split bf16 out) ----
    for (int node = blockIdx.x * 4 + w; node < N_NODES; node += G * 4)
        gather_node(node, lane, Z, perm64, counts, cursor, bavg,
                    (float*)nullptr, h1h, h1l, 1);
    grid.sync();

    // ---- phase 6: gemm layer 2 (pre-split bf16 input h1) ----
    for (int tile = blockIdx.x; tile < GEMM_TILES; tile += G)
        gemm_tile(tile * 64, 0, (const float*)nullptr, h1h, h1l,
                  Whsw + WELEM, Wlsw + WELEM, Z, AhS, AlS, tid, lane, w, quad, l15);
    grid.sync();

    // ---- phase 7: gather layer 2 (fp32 out) ----
    for (int node = blockIdx.x * 4 + w; node < N_NODES; node += G * 4)
        gather_node(node, lane, Z, perm64, counts, cursor, bavg + F,
                    outF, (unsigned short*)nullptr, (unsigned short*)nullptr, 0);
}

extern "C" void kernel_launch(void* const* d_in, const int* in_sizes, int n_in,
                              void* d_out, int out_size, void* d_ws, size_t ws_size,
                              hipStream_t stream)
{
    const float* x   = (const float*)d_in[0];
    const float* Ws1 = (const float*)d_in[1];
    const float* Wn1 = (const float*)d_in[2];
    const float* b1  = (const float*)d_in[3];
    const float* Ws2 = (const float*)d_in[4];
    const float* Wn2 = (const float*)d_in[5];
    const float* b2  = (const float*)d_in[6];
    const int* edge_index = (const int*)d_in[7];
    const int* edge_type  = (const int*)d_in[8];

    const int* srcA = edge_index;
    const int* dstA = edge_index + N_EDGES;
    const int* typA = edge_type;

    // workspace layout (keeps perm64 8B-aligned)
    unsigned short* Z   = (unsigned short*)d_ws;             // N*640 u16 = 64.0 MB
    unsigned short* h1h = Z + (size_t)N_NODES * ZC;          // N*128 u16
    unsigned short* h1l = h1h + (size_t)N_NODES * F;         // N*128 u16
    float* bavg = (float*)(h1l + (size_t)N_NODES * F);       // 256 f
    unsigned short* Whsw = (unsigned short*)(bavg + 2 * F);  // 2*WELEM u16
    unsigned short* Wlsw = Whsw + (size_t)2 * WELEM;         // 2*WELEM u16
    int* counts = (int*)(Wlsw + (size_t)2 * WELEM);          // N_SEG+2 (off + sentinel)
    int* cursor = counts + (N_SEG + 2);                      // N_SEG
    int* bsum   = cursor + N_SEG;                            // 256 (even int count)
    unsigned long long* perm64 = (unsigned long long*)(bsum + 256);  // N_EDGES u64
    float* outF = (float*)d_out;

    // co-residency clamp: query occupancy, cap at 3 blocks/CU
    int perCU = 0;
    hipOccupancyMaxActiveBlocksPerMultiprocessor(&perCU, (const void*)fused_all, 256, 0);
    if (perCU < 1) perCU = 1;
    if (perCU > 3) perCU = 3;
    int gridBlocks = 256 * perCU;

    void* args[] = {
        (void*)&x, (void*)&Ws1, (void*)&Wn1, (void*)&b1,
        (void*)&Ws2, (void*)&Wn2, (void*)&b2,
        (void*)&srcA, (void*)&dstA, (void*)&typA,
        (void*)&Z, (void*)&h1h, (void*)&h1l, (void*)&bavg,
        (void*)&Whsw, (void*)&Wlsw,
        (void*)&counts, (void*)&cursor, (void*)&bsum,
        (void*)&perm64, (void*)&outF
    };
    hipLaunchCooperativeKernel((const void*)fused_all, dim3(gridBlocks), dim3(256),
                               args, 0, stream);
}